// Round 1
// baseline (208.190 us; speedup 1.0000x reference)
//
#include <hip/hip_runtime.h>
#include <hip/hip_bf16.h>
#include <stdint.h>

#define M_TOT 16384
#define N_TOT 2048
#define K_TOT 2048
#define BM 128
#define BN 128
#define BK 32

typedef __attribute__((ext_vector_type(8))) short bf16x8;
typedef __attribute__((ext_vector_type(4))) float f32x4;

__device__ __forceinline__ ushort f32_to_bf16_rne(float f) {
    uint32_t u = __float_as_uint(f);
    uint32_t r = (u + 0x7fffu + ((u >> 16) & 1u)) >> 16;
    return (ushort)r;
}

__device__ __forceinline__ void async_copy16(const void* gptr, void* lptr) {
    __builtin_amdgcn_global_load_lds(
        (const __attribute__((address_space(1))) uint32_t*)gptr,
        (__attribute__((address_space(3))) uint32_t*)lptr,
        16, 0, 0);
}

// ---------------------------------------------------------------------------
// Fake-quantize x: per (row, 32-col) block, symmetric int8. 8 lanes per block,
// each lane owns one float4. Output bf16 (as ushort bits).
// ---------------------------------------------------------------------------
__global__ void quant_x_kernel(const float* __restrict__ x, ushort* __restrict__ qx) {
    const int tid = blockIdx.x * 256 + threadIdx.x;   // one float4 per thread
    const float4 v = ((const float4*)x)[tid];
    float m = fmaxf(fmaxf(fabsf(v.x), fabsf(v.y)), fmaxf(fabsf(v.z), fabsf(v.w)));
    // reduce maxabs across the 8 lanes that share a 32-element block
    m = fmaxf(m, __shfl_xor(m, 1));
    m = fmaxf(m, __shfl_xor(m, 2));
    m = fmaxf(m, __shfl_xor(m, 4));
    const float s = (m > 0.f) ? (m / 127.f) : 1.f;
    const float q0 = fminf(fmaxf(rintf(v.x / s), -127.f), 127.f) * s;
    const float q1 = fminf(fmaxf(rintf(v.y / s), -127.f), 127.f) * s;
    const float q2 = fminf(fmaxf(rintf(v.z / s), -127.f), 127.f) * s;
    const float q3 = fminf(fmaxf(rintf(v.w / s), -127.f), 127.f) * s;
    ushort4 r;
    r.x = f32_to_bf16_rne(q0);
    r.y = f32_to_bf16_rne(q1);
    r.z = f32_to_bf16_rne(q2);
    r.w = f32_to_bf16_rne(q3);
    ((ushort4*)qx)[tid] = r;
}

// ---------------------------------------------------------------------------
// Fake-quantize weight (kept in [Dout][Din] layout == B^T for the GEMM).
// Quant blocks of weight.T are (32 k) x (32 n)  ->  32x32 tiles of weight.
// One wave per tile; lane covers 16 consecutive floats of one row-half.
// ---------------------------------------------------------------------------
__global__ void quant_w_kernel(const float* __restrict__ w, ushort* __restrict__ qw) {
    const int gtid = blockIdx.x * 256 + threadIdx.x;
    const int wid  = gtid >> 6;        // tile id 0..4095
    const int lane = gtid & 63;
    const int tn = wid >> 6;           // n-block (row block of weight)
    const int tk = wid & 63;           // k-block (col block of weight)
    const int row = tn * 32 + (lane >> 1);
    const int col = tk * 32 + ((lane & 1) << 4);
    const float* p = w + (size_t)row * K_TOT + col;
    const float4 v0 = ((const float4*)p)[0];
    const float4 v1 = ((const float4*)p)[1];
    const float4 v2 = ((const float4*)p)[2];
    const float4 v3 = ((const float4*)p)[3];
    float m = 0.f;
#define MAX4(V) m = fmaxf(m, fmaxf(fmaxf(fabsf(V.x), fabsf(V.y)), fmaxf(fabsf(V.z), fabsf(V.w))));
    MAX4(v0) MAX4(v1) MAX4(v2) MAX4(v3)
#undef MAX4
    #pragma unroll
    for (int off = 1; off < 64; off <<= 1) m = fmaxf(m, __shfl_xor(m, off));
    const float s = (m > 0.f) ? (m / 127.f) : 1.f;
    float vv[16] = {v0.x, v0.y, v0.z, v0.w, v1.x, v1.y, v1.z, v1.w,
                    v2.x, v2.y, v2.z, v2.w, v3.x, v3.y, v3.z, v3.w};
    union { ushort us[16]; uint4 q[2]; } o;
    #pragma unroll
    for (int i = 0; i < 16; ++i) {
        const float q = fminf(fmaxf(rintf(vv[i] / s), -127.f), 127.f) * s;
        o.us[i] = f32_to_bf16_rne(q);
    }
    uint4* dst = (uint4*)(qw + (size_t)row * K_TOT + col);
    dst[0] = o.q[0];
    dst[1] = o.q[1];
}

// ---------------------------------------------------------------------------
// bf16 GEMM: C[M][N] = A[M][K] * Bt[N][K]^T + bias, m97 structure:
// 128x128 tile, BK=32, 4 waves (2x2 of 64x64), 16x16x32 MFMA,
// global_load_lds width-16 staging, 2 barriers per K-step.
// ---------------------------------------------------------------------------
__global__ __launch_bounds__(256) void gemm_bf16_kernel(
    const ushort* __restrict__ A,    // [M][K] quantized x (bf16 bits)
    const ushort* __restrict__ Bt,   // [N][K] quantized weight (bf16 bits)
    const float* __restrict__ bias,  // [N]
    float* __restrict__ C) {         // [M][N]

    __shared__ ushort As[BM][BK];    // 8 KB
    __shared__ ushort Bs[BN][BK];    // 8 KB

    const int tid  = threadIdx.x;
    const int lane = tid & 63;
    const int wave = tid >> 6;
    const int wr = wave >> 1;        // wave row (0..1)
    const int wc = wave & 1;         // wave col (0..1)
    const int r  = lane & 15;
    const int h  = lane >> 4;

    // bijective XCD swizzle (nwg = 2048, divisible by 8)
    const int nbn = N_TOT / BN;                    // 16
    const int nwg = (M_TOT / BM) * nbn;            // 2048
    const int bidx = blockIdx.x;
    const int cpx = nwg >> 3;
    const int swz = (bidx & 7) * cpx + (bidx >> 3);
    const int brow = (swz / nbn) * BM;
    const int bcol = (swz % nbn) * BN;

    f32x4 acc[4][4];
    const f32x4 zero = {0.f, 0.f, 0.f, 0.f};
    #pragma unroll
    for (int i = 0; i < 4; ++i)
        #pragma unroll
        for (int j = 0; j < 4; ++j) acc[i][j] = zero;

    // staging geometry: issue covers 64 rows; thread t -> row tid/4, col (tid%4)*8
    const int srow = tid >> 2;           // 0..63
    const int scol = (tid & 3) << 3;     // 0,8,16,24
    ushort* ldsA = &As[0][0] + (wave << 9);   // wave-uniform base (1 KB/wave chunk)
    ushort* ldsB = &Bs[0][0] + (wave << 9);

    for (int kt = 0; kt < K_TOT / BK; ++kt) {
        const int k0 = kt * BK + scol;
        __syncthreads();   // previous iter's LDS reads done
        async_copy16(A  + (size_t)(brow + srow     ) * K_TOT + k0, ldsA);
        async_copy16(A  + (size_t)(brow + srow + 64) * K_TOT + k0, ldsA + 2048);
        async_copy16(Bt + (size_t)(bcol + srow     ) * K_TOT + k0, ldsB);
        async_copy16(Bt + (size_t)(bcol + srow + 64) * K_TOT + k0, ldsB + 2048);
        __syncthreads();   // staging complete (compiler drains vmcnt)

        bf16x8 af[4], bg[4];
        #pragma unroll
        for (int m = 0; m < 4; ++m)
            af[m] = *(const bf16x8*)&As[wr * 64 + m * 16 + r][h * 8];
        #pragma unroll
        for (int n = 0; n < 4; ++n)
            bg[n] = *(const bf16x8*)&Bs[wc * 64 + n * 16 + r][h * 8];
        #pragma unroll
        for (int m = 0; m < 4; ++m)
            #pragma unroll
            for (int n = 0; n < 4; ++n)
                acc[m][n] = __builtin_amdgcn_mfma_f32_16x16x32_bf16(af[m], bg[n], acc[m][n], 0, 0, 0);
    }

    // epilogue: C/D layout col = lane&15, row = (lane>>4)*4 + reg
    #pragma unroll
    for (int m = 0; m < 4; ++m) {
        const int row0 = brow + wr * 64 + m * 16 + h * 4;
        #pragma unroll
        for (int n = 0; n < 4; ++n) {
            const int col = bcol + wc * 64 + n * 16 + r;
            const float bv = bias[col];
            #pragma unroll
            for (int j = 0; j < 4; ++j)
                C[(size_t)(row0 + j) * N_TOT + col] = acc[m][n][j] + bv;
        }
    }
}

extern "C" void kernel_launch(void* const* d_in, const int* in_sizes, int n_in,
                              void* d_out, int out_size, void* d_ws, size_t ws_size,
                              hipStream_t stream) {
    const float* x    = (const float*)d_in[0];   // [4,4096,2048]
    const float* w    = (const float*)d_in[1];   // [2048,2048]
    const float* bias = (const float*)d_in[2];   // [2048]
    float* out = (float*)d_out;                  // [4,4096,2048]

    ushort* qx = (ushort*)d_ws;                          // 16384*2048 bf16 = 64 MB
    ushort* qw = qx + (size_t)M_TOT * K_TOT;             // 2048*2048 bf16 = 8 MB

    quant_x_kernel<<<(M_TOT * K_TOT / 4) / 256, 256, 0, stream>>>(x, qx);
    quant_w_kernel<<<(64 * 64 * 64) / 256, 256, 0, stream>>>(w, qw);
    gemm_bf16_kernel<<<(M_TOT / BM) * (N_TOT / BN), 256, 0, stream>>>(qx, qw, bias, out);
}

// Round 2
// 203.803 us; speedup vs baseline: 1.0215x; 1.0215x over previous
//
#include <hip/hip_runtime.h>
#include <hip/hip_bf16.h>
#include <stdint.h>

#define M_TOT 16384
#define N_TOT 2048
#define K_TOT 2048
#define BK2 64
#define NT (K_TOT / BK2)   // 32 K-tiles

typedef __attribute__((ext_vector_type(8))) short bf16x8;
typedef __attribute__((ext_vector_type(4))) float f32x4;

__device__ __forceinline__ ushort f32_to_bf16_rne(float f) {
    uint32_t u = __float_as_uint(f);
    uint32_t r = (u + 0x7fffu + ((u >> 16) & 1u)) >> 16;
    return (ushort)r;
}

__device__ __forceinline__ void async_copy16(const void* gptr, void* lptr) {
    __builtin_amdgcn_global_load_lds(
        (const __attribute__((address_space(1))) uint32_t*)gptr,
        (__attribute__((address_space(3))) uint32_t*)lptr,
        16, 0, 0);
}

// ---------------------------------------------------------------------------
// Fake-quantize x: per (row, 32-col) block, symmetric int8 -> bf16.
// ---------------------------------------------------------------------------
__global__ void quant_x_kernel(const float* __restrict__ x, ushort* __restrict__ qx) {
    const int tid = blockIdx.x * 256 + threadIdx.x;
    const float4 v = ((const float4*)x)[tid];
    float m = fmaxf(fmaxf(fabsf(v.x), fabsf(v.y)), fmaxf(fabsf(v.z), fabsf(v.w)));
    m = fmaxf(m, __shfl_xor(m, 1));
    m = fmaxf(m, __shfl_xor(m, 2));
    m = fmaxf(m, __shfl_xor(m, 4));
    const float s = (m > 0.f) ? (m / 127.f) : 1.f;
    const float q0 = fminf(fmaxf(rintf(v.x / s), -127.f), 127.f) * s;
    const float q1 = fminf(fmaxf(rintf(v.y / s), -127.f), 127.f) * s;
    const float q2 = fminf(fmaxf(rintf(v.z / s), -127.f), 127.f) * s;
    const float q3 = fminf(fmaxf(rintf(v.w / s), -127.f), 127.f) * s;
    ushort4 r;
    r.x = f32_to_bf16_rne(q0);
    r.y = f32_to_bf16_rne(q1);
    r.z = f32_to_bf16_rne(q2);
    r.w = f32_to_bf16_rne(q3);
    ((ushort4*)qx)[tid] = r;
}

// ---------------------------------------------------------------------------
// Fake-quantize weight (kept [Dout][Din] == B^T layout). 32x32 blocks.
// ---------------------------------------------------------------------------
__global__ void quant_w_kernel(const float* __restrict__ w, ushort* __restrict__ qw) {
    const int gtid = blockIdx.x * 256 + threadIdx.x;
    const int wid  = gtid >> 6;
    const int lane = gtid & 63;
    const int tn = wid >> 6;
    const int tk = wid & 63;
    const int row = tn * 32 + (lane >> 1);
    const int col = tk * 32 + ((lane & 1) << 4);
    const float* p = w + (size_t)row * K_TOT + col;
    const float4 v0 = ((const float4*)p)[0];
    const float4 v1 = ((const float4*)p)[1];
    const float4 v2 = ((const float4*)p)[2];
    const float4 v3 = ((const float4*)p)[3];
    float m = 0.f;
#define MAX4(V) m = fmaxf(m, fmaxf(fmaxf(fabsf(V.x), fabsf(V.y)), fmaxf(fabsf(V.z), fabsf(V.w))));
    MAX4(v0) MAX4(v1) MAX4(v2) MAX4(v3)
#undef MAX4
    #pragma unroll
    for (int off = 1; off < 64; off <<= 1) m = fmaxf(m, __shfl_xor(m, off));
    const float s = (m > 0.f) ? (m / 127.f) : 1.f;
    float vv[16] = {v0.x, v0.y, v0.z, v0.w, v1.x, v1.y, v1.z, v1.w,
                    v2.x, v2.y, v2.z, v2.w, v3.x, v3.y, v3.z, v3.w};
    union { ushort us[16]; uint4 q[2]; } o;
    #pragma unroll
    for (int i = 0; i < 16; ++i) {
        const float q = fminf(fmaxf(rintf(vv[i] / s), -127.f), 127.f) * s;
        o.us[i] = f32_to_bf16_rne(q);
    }
    uint4* dst = (uint4*)(qw + (size_t)row * K_TOT + col);
    dst[0] = o.q[0];
    dst[1] = o.q[1];
}

// ---------------------------------------------------------------------------
// 256x256 8-phase bf16 GEMM (T2 swizzle + T3/T4 counted vmcnt + T5 setprio).
// C[M][N] = A[M][K] * Bt[N][K]^T + bias.
// 512 threads = 8 waves (2M x 4N), per-wave 128x64, BK=64, LDS 128 KB dbuf.
// ---------------------------------------------------------------------------
#define LDSA(b, row, colus) (*(const bf16x8*)&As[b][row][(colus) ^ (((row) & 7) << 3)])
#define LDSB(b, row, colus) (*(const bf16x8*)&Bs[b][row][(colus) ^ (((row) & 7) << 3)])

// stage one half-tile slice: thread covers row (hh*128 + li*64 + srow), 16B at
// pre-swizzled col; LDS dest is linear (wave-uniform base + lane*16).
#define STAGE_A(b, hh, li, tt)                                                     \
    async_copy16(Agbase + (size_t)((hh) * 128 + (li) * 64) * K_TOT + (size_t)(tt) * 64, \
                 (char*)&As[b][0][0] + (hh) * 16384 + (li) * 8192 + (w << 10))
#define STAGE_B(b, hh, li, tt)                                                     \
    async_copy16(Bgbase + (size_t)((hh) * 128 + (li) * 64) * K_TOT + (size_t)(tt) * 64, \
                 (char*)&Bs[b][0][0] + (hh) * 16384 + (li) * 8192 + (w << 10))

#define MFMA16(i0)                                                                        \
    __builtin_amdgcn_s_barrier();                                                         \
    asm volatile("s_waitcnt lgkmcnt(0)" ::: "memory");                                    \
    __builtin_amdgcn_s_setprio(1);                                                        \
    _Pragma("unroll")                                                                     \
    for (int j = 0; j < 4; ++j) {                                                         \
        acc[i0][j]     = __builtin_amdgcn_mfma_f32_16x16x32_bf16(af0, bg[j][0], acc[i0][j], 0, 0, 0);         \
        acc[i0][j]     = __builtin_amdgcn_mfma_f32_16x16x32_bf16(af1, bg[j][1], acc[i0][j], 0, 0, 0);         \
        acc[(i0)+1][j] = __builtin_amdgcn_mfma_f32_16x16x32_bf16(af2, bg[j][0], acc[(i0)+1][j], 0, 0, 0);     \
        acc[(i0)+1][j] = __builtin_amdgcn_mfma_f32_16x16x32_bf16(af3, bg[j][1], acc[(i0)+1][j], 0, 0, 0);     \
    }                                                                                     \
    __builtin_amdgcn_s_setprio(0);

__global__ __launch_bounds__(512, 1) void gemm_8phase_kernel(
    const ushort* __restrict__ A,    // [M][K] bf16 bits
    const ushort* __restrict__ Bt,   // [N][K] bf16 bits
    const float* __restrict__ bias,  // [N]
    float* __restrict__ C) {         // [M][N]

    __shared__ ushort As[2][256][64];   // 64 KB (2 bufs x 256 x 128B rows)
    __shared__ ushort Bs[2][256][64];   // 64 KB

    const int tid  = threadIdx.x;
    const int lane = tid & 63;
    const int w    = tid >> 6;          // wave 0..7
    const int wr   = w >> 2;            // 0..1  (M)
    const int wc   = w & 3;             // 0..3  (N)
    const int r    = lane & 15;
    const int h    = lane >> 4;         // 0..3

    // bijective XCD swizzle (nwg = 512)
    const int nbn  = N_TOT / 256;                 // 8
    const int nwg  = (M_TOT / 256) * nbn;         // 512
    const int cpx  = nwg >> 3;
    const int swz  = (blockIdx.x & 7) * cpx + (blockIdx.x >> 3);
    const int brow = (swz / nbn) * 256;
    const int bcol = (swz % nbn) * 256;

    // staging constants: thread covers 16B at (srow, scol) of each 64-row round;
    // source col pre-swizzled so linear LDS + XOR-read is consistent (rule #21).
    const int srow = tid >> 3;                            // 0..63
    const int scol = (((tid & 7) ^ (srow & 7)) << 3);     // ushorts
    const ushort* Agbase = A  + (size_t)(brow + srow) * K_TOT + scol;
    const ushort* Bgbase = Bt + (size_t)(bcol + srow) * K_TOT + scol;

    f32x4 acc[8][4];
    const f32x4 zero = {0.f, 0.f, 0.f, 0.f};
    #pragma unroll
    for (int i = 0; i < 8; ++i)
        #pragma unroll
        for (int j = 0; j < 4; ++j) acc[i][j] = zero;

    // ---- prologue: K-tile 0 (A+B) into buf0, B of K-tile 1 into buf1 ----
    STAGE_A(0, 0, 0, 0); STAGE_A(0, 0, 1, 0); STAGE_A(0, 1, 0, 0); STAGE_A(0, 1, 1, 0);
    STAGE_B(0, 0, 0, 0); STAGE_B(0, 0, 1, 0); STAGE_B(0, 1, 0, 0); STAGE_B(0, 1, 1, 0);
    STAGE_B(1, 0, 0, 1); STAGE_B(1, 0, 1, 1); STAGE_B(1, 1, 0, 1); STAGE_B(1, 1, 1, 1);
    asm volatile("s_waitcnt vmcnt(4)" ::: "memory");   // K-tile 0 landed; B(1) in flight
    __builtin_amdgcn_s_barrier();

    bf16x8 af0, af1, af2, af3;
    bf16x8 bg[4][2];
    const int ab = wr * 128 + r;   // wave's A row base

    for (int t = 0; t < NT; ++t) {
        const int buf = t & 1;
        const int nb  = buf ^ 1;

        // ---- phase 0: A rows 0,16 + all B frags; stage A(t+1) half0 -> nb ----
        af0 = LDSA(buf, ab +  0, h * 8);  af1 = LDSA(buf, ab +  0, 32 + h * 8);
        af2 = LDSA(buf, ab + 16, h * 8);  af3 = LDSA(buf, ab + 16, 32 + h * 8);
        #pragma unroll
        for (int j = 0; j < 4; ++j) {
            const int bb = wc * 64 + j * 16 + r;
            bg[j][0] = LDSB(buf, bb, h * 8);
            bg[j][1] = LDSB(buf, bb, 32 + h * 8);
        }
        if (t + 1 < NT) { STAGE_A(nb, 0, 0, t + 1); STAGE_A(nb, 0, 1, t + 1); }
        MFMA16(0)
        __builtin_amdgcn_s_barrier();

        // ---- phase 1: A rows 32,48; stage A(t+1) half1 -> nb ----
        af0 = LDSA(buf, ab + 32, h * 8);  af1 = LDSA(buf, ab + 32, 32 + h * 8);
        af2 = LDSA(buf, ab + 48, h * 8);  af3 = LDSA(buf, ab + 48, 32 + h * 8);
        if (t + 1 < NT) { STAGE_A(nb, 1, 0, t + 1); STAGE_A(nb, 1, 1, t + 1); }
        MFMA16(2)
        __builtin_amdgcn_s_barrier();

        // ---- phase 2: A rows 64,80; stage B(t+2) half0 -> buf (B region free after p0) ----
        af0 = LDSA(buf, ab + 64, h * 8);  af1 = LDSA(buf, ab + 64, 32 + h * 8);
        af2 = LDSA(buf, ab + 80, h * 8);  af3 = LDSA(buf, ab + 80, 32 + h * 8);
        if (t + 2 < NT) { STAGE_B(buf, 0, 0, t + 2); STAGE_B(buf, 0, 1, t + 2); }
        MFMA16(4)
        __builtin_amdgcn_s_barrier();

        // ---- phase 3: A rows 96,112; stage B(t+2) half1; counted vmcnt ----
        af0 = LDSA(buf, ab +  96, h * 8); af1 = LDSA(buf, ab +  96, 32 + h * 8);
        af2 = LDSA(buf, ab + 112, h * 8); af3 = LDSA(buf, ab + 112, 32 + h * 8);
        if (t + 2 < NT) { STAGE_B(buf, 1, 0, t + 2); STAGE_B(buf, 1, 1, t + 2); }
        MFMA16(6)
        if (t + 2 < NT) { asm volatile("s_waitcnt vmcnt(4)" ::: "memory"); }
        else            { asm volatile("s_waitcnt vmcnt(0)" ::: "memory"); }
        __builtin_amdgcn_s_barrier();
    }

    // ---- epilogue: bias + store (C/D layout: col=lane&15, row=h*4+reg) ----
    float bv[4];
    #pragma unroll
    for (int j = 0; j < 4; ++j) bv[j] = bias[bcol + wc * 64 + j * 16 + r];
    #pragma unroll
    for (int i = 0; i < 8; ++i) {
        const int row0 = brow + wr * 128 + i * 16 + h * 4;
        #pragma unroll
        for (int j = 0; j < 4; ++j) {
            const int col = bcol + wc * 64 + j * 16 + r;
            #pragma unroll
            for (int jj = 0; jj < 4; ++jj)
                C[(size_t)(row0 + jj) * N_TOT + col] = acc[i][j][jj] + bv[j];
        }
    }
}

extern "C" void kernel_launch(void* const* d_in, const int* in_sizes, int n_in,
                              void* d_out, int out_size, void* d_ws, size_t ws_size,
                              hipStream_t stream) {
    const float* x    = (const float*)d_in[0];   // [4,4096,2048]
    const float* wgt  = (const float*)d_in[1];   // [2048,2048]
    const float* bias = (const float*)d_in[2];   // [2048]
    float* out = (float*)d_out;                  // [4,4096,2048]

    ushort* qx = (ushort*)d_ws;                          // 64 MB
    ushort* qw = qx + (size_t)M_TOT * K_TOT;             // 8 MB

    quant_x_kernel<<<(M_TOT * K_TOT / 4) / 256, 256, 0, stream>>>(x, qx);
    quant_w_kernel<<<(64 * 64 * 64) / 256, 256, 0, stream>>>(wgt, qw);
    gemm_8phase_kernel<<<(M_TOT / 256) * (N_TOT / 256), 512, 0, stream>>>(qx, qw, bias, out);
}

// Round 3
// 187.129 us; speedup vs baseline: 1.1125x; 1.0891x over previous
//
#include <hip/hip_runtime.h>
#include <hip/hip_bf16.h>
#include <stdint.h>

#define M_TOT 16384
#define N_TOT 2048
#define K_TOT 2048
#define NT 32            // K-tiles of BK=64

typedef __attribute__((ext_vector_type(8))) short bf16x8;
typedef __attribute__((ext_vector_type(4))) float f32x4;

__device__ __forceinline__ ushort f32_to_bf16_rne(float f) {
    uint32_t u = __float_as_uint(f);
    uint32_t r = (u + 0x7fffu + ((u >> 16) & 1u)) >> 16;
    return (ushort)r;
}

__device__ __forceinline__ void async_copy16(const void* gptr, void* lptr) {
    __builtin_amdgcn_global_load_lds(
        (const __attribute__((address_space(1))) uint32_t*)gptr,
        (__attribute__((address_space(3))) uint32_t*)lptr,
        16, 0, 0);
}

// ---------------------------------------------------------------------------
// Fake-quantize x: per (row, 32-col) block, symmetric int8 -> bf16.
// ---------------------------------------------------------------------------
__global__ void quant_x_kernel(const float* __restrict__ x, ushort* __restrict__ qx) {
    const int tid = blockIdx.x * 256 + threadIdx.x;
    const float4 v = ((const float4*)x)[tid];
    float m = fmaxf(fmaxf(fabsf(v.x), fabsf(v.y)), fmaxf(fabsf(v.z), fabsf(v.w)));
    m = fmaxf(m, __shfl_xor(m, 1));
    m = fmaxf(m, __shfl_xor(m, 2));
    m = fmaxf(m, __shfl_xor(m, 4));
    const float s = (m > 0.f) ? (m / 127.f) : 1.f;
    const float q0 = fminf(fmaxf(rintf(v.x / s), -127.f), 127.f) * s;
    const float q1 = fminf(fmaxf(rintf(v.y / s), -127.f), 127.f) * s;
    const float q2 = fminf(fmaxf(rintf(v.z / s), -127.f), 127.f) * s;
    const float q3 = fminf(fmaxf(rintf(v.w / s), -127.f), 127.f) * s;
    ushort4 r;
    r.x = f32_to_bf16_rne(q0);
    r.y = f32_to_bf16_rne(q1);
    r.z = f32_to_bf16_rne(q2);
    r.w = f32_to_bf16_rne(q3);
    ((ushort4*)qx)[tid] = r;
}

// ---------------------------------------------------------------------------
// Fake-quantize weight (kept [Dout][Din] == B^T layout). 32x32 blocks.
// ---------------------------------------------------------------------------
__global__ void quant_w_kernel(const float* __restrict__ w, ushort* __restrict__ qw) {
    const int gtid = blockIdx.x * 256 + threadIdx.x;
    const int wid  = gtid >> 6;
    const int lane = gtid & 63;
    const int tn = wid >> 6;
    const int tk = wid & 63;
    const int row = tn * 32 + (lane >> 1);
    const int col = tk * 32 + ((lane & 1) << 4);
    const float* p = w + (size_t)row * K_TOT + col;
    const float4 v0 = ((const float4*)p)[0];
    const float4 v1 = ((const float4*)p)[1];
    const float4 v2 = ((const float4*)p)[2];
    const float4 v3 = ((const float4*)p)[3];
    float m = 0.f;
#define MAX4(V) m = fmaxf(m, fmaxf(fmaxf(fabsf(V.x), fabsf(V.y)), fmaxf(fabsf(V.z), fabsf(V.w))));
    MAX4(v0) MAX4(v1) MAX4(v2) MAX4(v3)
#undef MAX4
    #pragma unroll
    for (int off = 1; off < 64; off <<= 1) m = fmaxf(m, __shfl_xor(m, off));
    const float s = (m > 0.f) ? (m / 127.f) : 1.f;
    float vv[16] = {v0.x, v0.y, v0.z, v0.w, v1.x, v1.y, v1.z, v1.w,
                    v2.x, v2.y, v2.z, v2.w, v3.x, v3.y, v3.z, v3.w};
    union { ushort us[16]; uint4 q[2]; } o;
    #pragma unroll
    for (int i = 0; i < 16; ++i) {
        const float q = fminf(fmaxf(rintf(vv[i] / s), -127.f), 127.f) * s;
        o.us[i] = f32_to_bf16_rne(q);
    }
    uint4* dst = (uint4*)(qw + (size_t)row * K_TOT + col);
    dst[0] = o.q[0];
    dst[1] = o.q[1];
}

// ---------------------------------------------------------------------------
// 256x256 software-pipelined bf16 GEMM.
// 8 waves (2M x 4N), per-wave 128x64, BK=64.  LDS: A double-buf + B TRIPLE-buf
// (160 KB).  bg (B-fragments) register-double-buffered across K-tiles so each
// phase issues only {4 af reads + 2 bg-next reads + 2 stage} and MFMA overlaps
// the LDS pipe.  One counted vmcnt(2) per tile at phase 2.
// ---------------------------------------------------------------------------
#define LDSA(tb, row, colus) \
    (*(const bf16x8*)&As[tb][row][(colus) ^ (((row) & 7) << 3)])
#define LDSB(slot, row, colus) \
    (*(const bf16x8*)&BsF[(size_t)(slot) * 16384 + (size_t)(row) * 64 + (((colus) ^ (((row) & 7) << 3)))])

// stage: thread covers 16B at (64-row-group, srow, pre-swizzled col); LDS dest
// linear (wave-uniform base + lane*16).
#define STAGE_A(tb, hh, li, tt)                                                          \
    async_copy16(Agbase + (size_t)((hh) * 128 + (li) * 64) * K_TOT + (size_t)(tt) * 64,  \
                 (char*)&As[0][0][0] + (tb) * 32768 + (hh) * 16384 + (li) * 8192 + (wv << 10))
#define STAGE_B(slot, hh, li, tt)                                                        \
    async_copy16(Bgbase + (size_t)((hh) * 128 + (li) * 64) * K_TOT + (size_t)(tt) * 64,  \
                 (char*)&BsF[0] + (size_t)(slot) * 32768 + (hh) * 16384 + (li) * 8192 + (wv << 10))

#define PHASE_MFMA(i0, BGC)                                                               \
    asm volatile("s_waitcnt lgkmcnt(0)" ::: "memory");                                    \
    __builtin_amdgcn_s_setprio(1);                                                        \
    _Pragma("unroll")                                                                     \
    for (int j = 0; j < 4; ++j) {                                                         \
        acc[i0][j]     = __builtin_amdgcn_mfma_f32_16x16x32_bf16(af0, BGC[j][0], acc[i0][j], 0, 0, 0);     \
        acc[i0][j]     = __builtin_amdgcn_mfma_f32_16x16x32_bf16(af1, BGC[j][1], acc[i0][j], 0, 0, 0);     \
        acc[(i0)+1][j] = __builtin_amdgcn_mfma_f32_16x16x32_bf16(af2, BGC[j][0], acc[(i0)+1][j], 0, 0, 0); \
        acc[(i0)+1][j] = __builtin_amdgcn_mfma_f32_16x16x32_bf16(af3, BGC[j][1], acc[(i0)+1][j], 0, 0, 0); \
    }                                                                                     \
    __builtin_amdgcn_s_setprio(0);

// One K-tile = 4 phases.  tb is compile-time (loop x2-unrolled).  BGC holds
// bg(t) (loaded last tile); BGN receives bg(t+1).  Stage: A(t+1) p0-p1 -> As[tb^1],
// B(t+3) p2-p3 -> Bs[bwr].  vmcnt(2) at p2 drains B(t+2)+A(t+1), keeps B(t+3) in flight.
#define TILE_BODY(tb, BGC, BGN, t)                                                        \
  {                                                                                       \
    /* phase 0 */                                                                         \
    af0 = LDSA(tb, ab +  0, h8);  af1 = LDSA(tb, ab +  0, 32 + h8);                       \
    af2 = LDSA(tb, ab + 16, h8);  af3 = LDSA(tb, ab + 16, 32 + h8);                       \
    if ((t) + 1 < NT) {                                                                   \
        BGN[0][0] = LDSB(brd, bb0, h8);  BGN[0][1] = LDSB(brd, bb0, 32 + h8);             \
        STAGE_A(tb ^ 1, 0, 0, (t) + 1);  STAGE_A(tb ^ 1, 0, 1, (t) + 1);                  \
    }                                                                                     \
    PHASE_MFMA(0, BGC)                                                                    \
    __builtin_amdgcn_s_barrier();                                                         \
    /* phase 1 */                                                                         \
    af0 = LDSA(tb, ab + 32, h8);  af1 = LDSA(tb, ab + 32, 32 + h8);                       \
    af2 = LDSA(tb, ab + 48, h8);  af3 = LDSA(tb, ab + 48, 32 + h8);                       \
    if ((t) + 1 < NT) {                                                                   \
        BGN[1][0] = LDSB(brd, bb1, h8);  BGN[1][1] = LDSB(brd, bb1, 32 + h8);             \
        STAGE_A(tb ^ 1, 1, 0, (t) + 1);  STAGE_A(tb ^ 1, 1, 1, (t) + 1);                  \
    }                                                                                     \
    PHASE_MFMA(2, BGC)                                                                    \
    __builtin_amdgcn_s_barrier();                                                         \
    /* phase 2 */                                                                         \
    af0 = LDSA(tb, ab + 64, h8);  af1 = LDSA(tb, ab + 64, 32 + h8);                       \
    af2 = LDSA(tb, ab + 80, h8);  af3 = LDSA(tb, ab + 80, 32 + h8);                       \
    if ((t) + 1 < NT) {                                                                   \
        BGN[2][0] = LDSB(brd, bb2, h8);  BGN[2][1] = LDSB(brd, bb2, 32 + h8);             \
    }                                                                                     \
    if ((t) + 3 < NT) { STAGE_B(bwr, 0, 0, (t) + 3);  STAGE_B(bwr, 0, 1, (t) + 3); }      \
    PHASE_MFMA(4, BGC)                                                                    \
    if ((t) + 3 < NT) { asm volatile("s_waitcnt vmcnt(2)" ::: "memory"); }                \
    else              { asm volatile("s_waitcnt vmcnt(0)" ::: "memory"); }                \
    __builtin_amdgcn_s_barrier();                                                         \
    /* phase 3 */                                                                         \
    af0 = LDSA(tb, ab +  96, h8);  af1 = LDSA(tb, ab +  96, 32 + h8);                     \
    af2 = LDSA(tb, ab + 112, h8);  af3 = LDSA(tb, ab + 112, 32 + h8);                     \
    if ((t) + 1 < NT) {                                                                   \
        BGN[3][0] = LDSB(brd, bb3, h8);  BGN[3][1] = LDSB(brd, bb3, 32 + h8);             \
    }                                                                                     \
    if ((t) + 3 < NT) { STAGE_B(bwr, 1, 0, (t) + 3);  STAGE_B(bwr, 1, 1, (t) + 3); }      \
    PHASE_MFMA(6, BGC)                                                                    \
    __builtin_amdgcn_s_barrier();                                                         \
  }

__global__ __launch_bounds__(512, 1) void gemm_pipe_kernel(
    const ushort* __restrict__ A,    // [M][K] bf16 bits
    const ushort* __restrict__ Bt,   // [N][K] bf16 bits
    const float* __restrict__ bias,  // [N]
    float* __restrict__ C) {         // [M][N]

    __shared__ ushort As[2][256][64];   // 64 KB
    __shared__ ushort Bs[3][256][64];   // 96 KB (triple-buffered B)
    const ushort* BsF = &Bs[0][0][0];

    const int tid  = threadIdx.x;
    const int lane = tid & 63;
    const int wv   = tid >> 6;          // wave 0..7
    const int wmr  = wv >> 2;           // 0..1  (M)
    const int wcn  = wv & 3;            // 0..3  (N)
    const int r    = lane & 15;
    const int h8   = (lane >> 4) << 3;  // 0,8,16,24 (ushort col of k-frag)

    // bijective XCD swizzle (nwg = 512)
    const int nbn  = N_TOT / 256;                 // 8
    const int nwg  = (M_TOT / 256) * nbn;         // 512
    const int cpx  = nwg >> 3;
    const int swz  = (blockIdx.x & 7) * cpx + (blockIdx.x >> 3);
    const int brow = (swz / nbn) * 256;
    const int bcol = (swz % nbn) * 256;

    // staging: thread -> row tid>>3 of each 64-row group, 16B at pre-swizzled col
    const int srow = tid >> 3;
    const int scol = (((tid & 7) ^ (srow & 7)) << 3);
    const ushort* Agbase = A  + (size_t)(brow + srow) * K_TOT + scol;
    const ushort* Bgbase = Bt + (size_t)(bcol + srow) * K_TOT + scol;

    const int ab  = wmr * 128 + r;      // wave's A row base
    const int bb0 = wcn * 64 +  0 + r;
    const int bb1 = wcn * 64 + 16 + r;
    const int bb2 = wcn * 64 + 32 + r;
    const int bb3 = wcn * 64 + 48 + r;

    f32x4 acc[8][4];
    const f32x4 zero = {0.f, 0.f, 0.f, 0.f};
    #pragma unroll
    for (int i = 0; i < 8; ++i)
        #pragma unroll
        for (int j = 0; j < 4; ++j) acc[i][j] = zero;

    // ---- prologue: A(0)->As0, B(0)->slot0, B(1)->slot1; drain; B(2)->slot2 in flight
    STAGE_A(0, 0, 0, 0); STAGE_A(0, 0, 1, 0); STAGE_A(0, 1, 0, 0); STAGE_A(0, 1, 1, 0);
    STAGE_B(0, 0, 0, 0); STAGE_B(0, 0, 1, 0); STAGE_B(0, 1, 0, 0); STAGE_B(0, 1, 1, 0);
    STAGE_B(1, 0, 0, 1); STAGE_B(1, 0, 1, 1); STAGE_B(1, 1, 0, 1); STAGE_B(1, 1, 1, 1);
    asm volatile("s_waitcnt vmcnt(0)" ::: "memory");
    STAGE_B(2, 0, 0, 2); STAGE_B(2, 0, 1, 2); STAGE_B(2, 1, 0, 2); STAGE_B(2, 1, 1, 2);
    __builtin_amdgcn_s_barrier();

    bf16x8 af0, af1, af2, af3;
    bf16x8 bgA[4][2], bgB[4][2];

    // preload bg(0) from slot 0
    bgA[0][0] = LDSB(0, bb0, h8);  bgA[0][1] = LDSB(0, bb0, 32 + h8);
    bgA[1][0] = LDSB(0, bb1, h8);  bgA[1][1] = LDSB(0, bb1, 32 + h8);
    bgA[2][0] = LDSB(0, bb2, h8);  bgA[2][1] = LDSB(0, bb2, 32 + h8);
    bgA[3][0] = LDSB(0, bb3, h8);  bgA[3][1] = LDSB(0, bb3, 32 + h8);

    int brd = 1;   // bg(t+1) read slot  = (t+1)%3
    int bwr = 0;   // B(t+3) write slot  = t%3

    for (int t = 0; t < NT; t += 2) {
        TILE_BODY(0, bgA, bgB, t)
        brd = (brd == 2) ? 0 : brd + 1;  bwr = (bwr == 2) ? 0 : bwr + 1;
        TILE_BODY(1, bgB, bgA, t + 1)
        brd = (brd == 2) ? 0 : brd + 1;  bwr = (bwr == 2) ? 0 : bwr + 1;
    }

    // ---- epilogue: bias + store (C/D layout: col=lane&15, row=(lane>>4)*4+reg)
    const int hq = (lane >> 4) * 4;
    float bv[4];
    #pragma unroll
    for (int j = 0; j < 4; ++j) bv[j] = bias[bcol + wcn * 64 + j * 16 + r];
    #pragma unroll
    for (int i = 0; i < 8; ++i) {
        const int row0 = brow + wmr * 128 + i * 16 + hq;
        #pragma unroll
        for (int j = 0; j < 4; ++j) {
            const int col = bcol + wcn * 64 + j * 16 + r;
            #pragma unroll
            for (int jj = 0; jj < 4; ++jj)
                C[(size_t)(row0 + jj) * N_TOT + col] = acc[i][j][jj] + bv[j];
        }
    }
}

extern "C" void kernel_launch(void* const* d_in, const int* in_sizes, int n_in,
                              void* d_out, int out_size, void* d_ws, size_t ws_size,
                              hipStream_t stream) {
    const float* x    = (const float*)d_in[0];   // [4,4096,2048]
    const float* wgt  = (const float*)d_in[1];   // [2048,2048]
    const float* bias = (const float*)d_in[2];   // [2048]
    float* out = (float*)d_out;                  // [4,4096,2048]

    ushort* qx = (ushort*)d_ws;                          // 64 MB
    ushort* qw = qx + (size_t)M_TOT * K_TOT;             // 8 MB

    quant_x_kernel<<<(M_TOT * K_TOT / 4) / 256, 256, 0, stream>>>(x, qx);
    quant_w_kernel<<<(64 * 64 * 64) / 256, 256, 0, stream>>>(wgt, qw);
    gemm_pipe_kernel<<<(M_TOT / 256) * (N_TOT / 256), 512, 0, stream>>>(qx, qw, bias, out);
}

// Round 4
// 175.278 us; speedup vs baseline: 1.1878x; 1.0676x over previous
//
#include <hip/hip_runtime.h>
#include <hip/hip_bf16.h>
#include <stdint.h>

#define M_TOT 16384
#define N_TOT 2048
#define K_TOT 2048
#define NT 32            // K-tiles of BK=64

typedef __attribute__((ext_vector_type(8))) short bf16x8;
typedef __attribute__((ext_vector_type(4))) float f32x4;

__device__ __forceinline__ ushort f32_to_bf16_rne(float f) {
    uint32_t u = __float_as_uint(f);
    uint32_t r = (u + 0x7fffu + ((u >> 16) & 1u)) >> 16;
    return (ushort)r;
}

__device__ __forceinline__ void async_copy16(const void* gptr, void* lptr) {
    __builtin_amdgcn_global_load_lds(
        (const __attribute__((address_space(1))) uint32_t*)gptr,
        (__attribute__((address_space(3))) uint32_t*)lptr,
        16, 0, 0);
}

// ---------------------------------------------------------------------------
// Fake-quantize x: per (row, 32-col) block, symmetric int8 -> bf16.
// ---------------------------------------------------------------------------
__global__ void quant_x_kernel(const float* __restrict__ x, ushort* __restrict__ qx) {
    const int tid = blockIdx.x * 256 + threadIdx.x;
    const float4 v = ((const float4*)x)[tid];
    float m = fmaxf(fmaxf(fabsf(v.x), fabsf(v.y)), fmaxf(fabsf(v.z), fabsf(v.w)));
    m = fmaxf(m, __shfl_xor(m, 1));
    m = fmaxf(m, __shfl_xor(m, 2));
    m = fmaxf(m, __shfl_xor(m, 4));
    const float s = (m > 0.f) ? (m / 127.f) : 1.f;
    const float q0 = fminf(fmaxf(rintf(v.x / s), -127.f), 127.f) * s;
    const float q1 = fminf(fmaxf(rintf(v.y / s), -127.f), 127.f) * s;
    const float q2 = fminf(fmaxf(rintf(v.z / s), -127.f), 127.f) * s;
    const float q3 = fminf(fmaxf(rintf(v.w / s), -127.f), 127.f) * s;
    ushort4 r;
    r.x = f32_to_bf16_rne(q0);
    r.y = f32_to_bf16_rne(q1);
    r.z = f32_to_bf16_rne(q2);
    r.w = f32_to_bf16_rne(q3);
    ((ushort4*)qx)[tid] = r;
}

// ---------------------------------------------------------------------------
// Fake-quantize weight (kept [Dout][Din] == B^T layout). 32x32 blocks.
// ---------------------------------------------------------------------------
__global__ void quant_w_kernel(const float* __restrict__ w, ushort* __restrict__ qw) {
    const int gtid = blockIdx.x * 256 + threadIdx.x;
    const int wid  = gtid >> 6;
    const int lane = gtid & 63;
    const int tn = wid >> 6;
    const int tk = wid & 63;
    const int row = tn * 32 + (lane >> 1);
    const int col = tk * 32 + ((lane & 1) << 4);
    const float* p = w + (size_t)row * K_TOT + col;
    const float4 v0 = ((const float4*)p)[0];
    const float4 v1 = ((const float4*)p)[1];
    const float4 v2 = ((const float4*)p)[2];
    const float4 v3 = ((const float4*)p)[3];
    float m = 0.f;
#define MAX4(V) m = fmaxf(m, fmaxf(fmaxf(fabsf(V.x), fabsf(V.y)), fmaxf(fabsf(V.z), fabsf(V.w))));
    MAX4(v0) MAX4(v1) MAX4(v2) MAX4(v3)
#undef MAX4
    #pragma unroll
    for (int off = 1; off < 64; off <<= 1) m = fmaxf(m, __shfl_xor(m, off));
    const float s = (m > 0.f) ? (m / 127.f) : 1.f;
    float vv[16] = {v0.x, v0.y, v0.z, v0.w, v1.x, v1.y, v1.z, v1.w,
                    v2.x, v2.y, v2.z, v2.w, v3.x, v3.y, v3.z, v3.w};
    union { ushort us[16]; uint4 q[2]; } o;
    #pragma unroll
    for (int i = 0; i < 16; ++i) {
        const float q = fminf(fmaxf(rintf(vv[i] / s), -127.f), 127.f) * s;
        o.us[i] = f32_to_bf16_rne(q);
    }
    uint4* dst = (uint4*)(qw + (size_t)row * K_TOT + col);
    dst[0] = o.q[0];
    dst[1] = o.q[1];
}

// ---------------------------------------------------------------------------
// 256x256 8-phase bf16 GEMM — faithful m201-template port.
// 8 waves (2M x 4N), per-wave 128x64, BK=64, LDS 2-buf A + 2-buf B = 128 KB.
// Phase = { ds-reads, 1 half-tile stage, [lgkm hint], barrier, lgkmcnt(0),
//           setprio(1), 16 MFMA, setprio(0), barrier }.  One counted vmcnt(4)
// per K-tile at phase 3 (A(t+1)+B(t+1) drained, B(t+2) stays in flight).
// ---------------------------------------------------------------------------
#define LDSA(tb, row, colus) \
    (*(const bf16x8*)&As[tb][row][(colus) ^ (((row) & 7) << 3)])
#define LDSB(tb, row, colus) \
    (*(const bf16x8*)&Bs[tb][row][(colus) ^ (((row) & 7) << 3)])

// stage one 64-row slice (all 512 threads, 16B each); LDS dest linear.
#define STAGE_A(tb, hh, li, tt)                                                          \
    async_copy16(Agbase + (size_t)((hh) * 128 + (li) * 64) * K_TOT + (size_t)(tt) * 64,  \
                 (char*)&As[0][0][0] + (tb) * 32768 + (hh) * 16384 + (li) * 8192 + (wv << 10))
#define STAGE_B(tb, hh, li, tt)                                                          \
    async_copy16(Bgbase + (size_t)((hh) * 128 + (li) * 64) * K_TOT + (size_t)(tt) * 64,  \
                 (char*)&Bs[0][0][0] + (tb) * 32768 + (hh) * 16384 + (li) * 8192 + (wv << 10))
#define STAGE_A2(tb, hh, tt)  { STAGE_A(tb, hh, 0, tt); STAGE_A(tb, hh, 1, tt); }
#define STAGE_B2(tb, hh, tt)  { STAGE_B(tb, hh, 0, tt); STAGE_B(tb, hh, 1, tt); }

#define PHASE_MFMA(i0)                                                                    \
    asm volatile("s_waitcnt lgkmcnt(0)" ::: "memory");                                    \
    __builtin_amdgcn_s_setprio(1);                                                        \
    _Pragma("unroll")                                                                     \
    for (int j = 0; j < 4; ++j) {                                                         \
        acc[i0][j]     = __builtin_amdgcn_mfma_f32_16x16x32_bf16(af0, bg[j][0], acc[i0][j], 0, 0, 0);     \
        acc[i0][j]     = __builtin_amdgcn_mfma_f32_16x16x32_bf16(af1, bg[j][1], acc[i0][j], 0, 0, 0);     \
        acc[(i0)+1][j] = __builtin_amdgcn_mfma_f32_16x16x32_bf16(af2, bg[j][0], acc[(i0)+1][j], 0, 0, 0); \
        acc[(i0)+1][j] = __builtin_amdgcn_mfma_f32_16x16x32_bf16(af3, bg[j][1], acc[(i0)+1][j], 0, 0, 0); \
    }                                                                                     \
    __builtin_amdgcn_s_setprio(0);

#define TILE_BODY(tb, t)                                                                  \
  {                                                                                       \
    bf16x8 af0, af1, af2, af3;                                                            \
    bf16x8 bg[4][2];                                                                      \
    /* ---- phase 0: af rows 0,16 + all 8 bg; stage A(t+1) half0 ---- */                  \
    af0 = LDSA(tb, ab +  0, h8);  af1 = LDSA(tb, ab +  0, 32 + h8);                       \
    af2 = LDSA(tb, ab + 16, h8);  af3 = LDSA(tb, ab + 16, 32 + h8);                       \
    bg[0][0] = LDSB(tb, bb0, h8);  bg[0][1] = LDSB(tb, bb0, 32 + h8);                     \
    bg[1][0] = LDSB(tb, bb1, h8);  bg[1][1] = LDSB(tb, bb1, 32 + h8);                     \
    bg[2][0] = LDSB(tb, bb2, h8);  bg[2][1] = LDSB(tb, bb2, 32 + h8);                     \
    bg[3][0] = LDSB(tb, bb3, h8);  bg[3][1] = LDSB(tb, bb3, 32 + h8);                     \
    if ((t) + 1 < NT) STAGE_A2(tb ^ 1, 0, (t) + 1)                                        \
    asm volatile("s_waitcnt lgkmcnt(8)" ::: "memory");                                    \
    __builtin_amdgcn_s_barrier();                                                         \
    PHASE_MFMA(0)                                                                         \
    __builtin_amdgcn_s_barrier();                                                         \
    /* ---- phase 1: af rows 32,48; stage A(t+1) half1 ---- */                            \
    af0 = LDSA(tb, ab + 32, h8);  af1 = LDSA(tb, ab + 32, 32 + h8);                       \
    af2 = LDSA(tb, ab + 48, h8);  af3 = LDSA(tb, ab + 48, 32 + h8);                       \
    if ((t) + 1 < NT) STAGE_A2(tb ^ 1, 1, (t) + 1)                                        \
    __builtin_amdgcn_s_barrier();                                                         \
    PHASE_MFMA(2)                                                                         \
    __builtin_amdgcn_s_barrier();                                                         \
    /* ---- phase 2: af rows 64,80; stage B(t+2) half0 (B reads done at p0) ---- */       \
    af0 = LDSA(tb, ab + 64, h8);  af1 = LDSA(tb, ab + 64, 32 + h8);                       \
    af2 = LDSA(tb, ab + 80, h8);  af3 = LDSA(tb, ab + 80, 32 + h8);                       \
    if ((t) + 2 < NT) STAGE_B2(tb, 0, (t) + 2)                                            \
    __builtin_amdgcn_s_barrier();                                                         \
    PHASE_MFMA(4)                                                                         \
    __builtin_amdgcn_s_barrier();                                                         \
    /* ---- phase 3: af rows 96,112; stage B(t+2) half1; counted vmcnt ---- */            \
    af0 = LDSA(tb, ab +  96, h8);  af1 = LDSA(tb, ab +  96, 32 + h8);                     \
    af2 = LDSA(tb, ab + 112, h8);  af3 = LDSA(tb, ab + 112, 32 + h8);                     \
    if ((t) + 2 < NT) STAGE_B2(tb, 1, (t) + 2)                                            \
    __builtin_amdgcn_s_barrier();                                                         \
    PHASE_MFMA(6)                                                                         \
    if ((t) + 2 < NT) { asm volatile("s_waitcnt vmcnt(4)" ::: "memory"); }                \
    else              { asm volatile("s_waitcnt vmcnt(0)" ::: "memory"); }                \
    __builtin_amdgcn_s_barrier();                                                         \
  }

__global__ __launch_bounds__(512, 1) void gemm_8ph_kernel(
    const ushort* __restrict__ A,    // [M][K] bf16 bits
    const ushort* __restrict__ Bt,   // [N][K] bf16 bits
    const float* __restrict__ bias,  // [N]
    float* __restrict__ C) {         // [M][N]

    __shared__ ushort As[2][256][64];   // 64 KB
    __shared__ ushort Bs[2][256][64];   // 64 KB

    const int tid  = threadIdx.x;
    const int lane = tid & 63;
    const int wv   = tid >> 6;          // wave 0..7
    const int wmr  = wv >> 2;           // 0..1  (M)
    const int wcn  = wv & 3;            // 0..3  (N)
    const int r    = lane & 15;
    const int h8   = (lane >> 4) << 3;  // 0,8,16,24 (ushort col of k-frag)

    // bijective XCD swizzle (nwg = 512)
    const int nbn  = N_TOT / 256;                 // 8
    const int nwg  = (M_TOT / 256) * nbn;         // 512
    const int cpx  = nwg >> 3;
    const int swz  = (blockIdx.x & 7) * cpx + (blockIdx.x >> 3);
    const int brow = (swz / nbn) * 256;
    const int bcol = (swz % nbn) * 256;

    // staging: thread -> row tid>>3 of each 64-row group, 16B at pre-swizzled col
    const int srow = tid >> 3;
    const int scol = (((tid & 7) ^ (srow & 7)) << 3);
    const ushort* Agbase = A  + (size_t)(brow + srow) * K_TOT + scol;
    const ushort* Bgbase = Bt + (size_t)(bcol + srow) * K_TOT + scol;

    const int ab  = wmr * 128 + r;      // wave's A row base
    const int bb0 = wcn * 64 +  0 + r;
    const int bb1 = wcn * 64 + 16 + r;
    const int bb2 = wcn * 64 + 32 + r;
    const int bb3 = wcn * 64 + 48 + r;

    f32x4 acc[8][4];
    const f32x4 zero = {0.f, 0.f, 0.f, 0.f};
    #pragma unroll
    for (int i = 0; i < 8; ++i)
        #pragma unroll
        for (int j = 0; j < 4; ++j) acc[i][j] = zero;

    // ---- prologue: A(0)+B(0) -> buf0, B(1) -> buf1; drain tile0, keep B(1) in flight
    STAGE_A2(0, 0, 0) STAGE_A2(0, 1, 0)
    STAGE_B2(0, 0, 0) STAGE_B2(0, 1, 0)
    STAGE_B2(1, 0, 1) STAGE_B2(1, 1, 1)
    asm volatile("s_waitcnt vmcnt(4)" ::: "memory");
    __builtin_amdgcn_s_barrier();

    for (int t = 0; t < NT; t += 2) {
        TILE_BODY(0, t)
        TILE_BODY(1, t + 1)
    }

    // ---- epilogue: bias + store (C/D layout: col=lane&15, row=(lane>>4)*4+reg)
    const int hq = (lane >> 4) * 4;
    float bv[4];
    #pragma unroll
    for (int j = 0; j < 4; ++j) bv[j] = bias[bcol + wcn * 64 + j * 16 + r];
    #pragma unroll
    for (int i = 0; i < 8; ++i) {
        const int row0 = brow + wmr * 128 + i * 16 + hq;
        #pragma unroll
        for (int j = 0; j < 4; ++j) {
            const int col = bcol + wcn * 64 + j * 16 + r;
            #pragma unroll
            for (int jj = 0; jj < 4; ++jj)
                C[(size_t)(row0 + jj) * N_TOT + col] = acc[i][j][jj] + bv[j];
        }
    }
}

extern "C" void kernel_launch(void* const* d_in, const int* in_sizes, int n_in,
                              void* d_out, int out_size, void* d_ws, size_t ws_size,
                              hipStream_t stream) {
    const float* x    = (const float*)d_in[0];   // [4,4096,2048]
    const float* wgt  = (const float*)d_in[1];   // [2048,2048]
    const float* bias = (const float*)d_in[2];   // [2048]
    float* out = (float*)d_out;                  // [4,4096,2048]

    ushort* qx = (ushort*)d_ws;                          // 64 MB
    ushort* qw = qx + (size_t)M_TOT * K_TOT;             // 8 MB

    quant_x_kernel<<<(M_TOT * K_TOT / 4) / 256, 256, 0, stream>>>(x, qx);
    quant_w_kernel<<<(64 * 64 * 64) / 256, 256, 0, stream>>>(wgt, qw);
    gemm_8ph_kernel<<<(M_TOT / 256) * (N_TOT / 256), 512, 0, stream>>>(qx, qw, bias, out);
}

// Round 5
// 166.268 us; speedup vs baseline: 1.2521x; 1.0542x over previous
//
#include <hip/hip_runtime.h>
#include <hip/hip_bf16.h>
#include <stdint.h>

#define M_TOT 16384
#define N_TOT 2048
#define K_TOT 2048
#define NT 32            // K-tiles of BK=64

typedef __attribute__((ext_vector_type(8))) short bf16x8;
typedef __attribute__((ext_vector_type(4))) float f32x4;

__device__ __forceinline__ ushort f32_to_bf16_rne(float f) {
    uint32_t u = __float_as_uint(f);
    uint32_t r = (u + 0x7fffu + ((u >> 16) & 1u)) >> 16;
    return (ushort)r;
}

__device__ __forceinline__ void async_copy16(const void* gptr, void* lptr) {
    __builtin_amdgcn_global_load_lds(
        (const __attribute__((address_space(1))) uint32_t*)gptr,
        (__attribute__((address_space(3))) uint32_t*)lptr,
        16, 0, 0);
}

// ---------------------------------------------------------------------------
// Fake-quantize x: per (row, 32-col) block, symmetric int8 -> bf16.
// ---------------------------------------------------------------------------
__global__ void quant_x_kernel(const float* __restrict__ x, ushort* __restrict__ qx) {
    const int tid = blockIdx.x * 256 + threadIdx.x;
    const float4 v = ((const float4*)x)[tid];
    float m = fmaxf(fmaxf(fabsf(v.x), fabsf(v.y)), fmaxf(fabsf(v.z), fabsf(v.w)));
    m = fmaxf(m, __shfl_xor(m, 1));
    m = fmaxf(m, __shfl_xor(m, 2));
    m = fmaxf(m, __shfl_xor(m, 4));
    const float s = (m > 0.f) ? (m / 127.f) : 1.f;
    const float q0 = fminf(fmaxf(rintf(v.x / s), -127.f), 127.f) * s;
    const float q1 = fminf(fmaxf(rintf(v.y / s), -127.f), 127.f) * s;
    const float q2 = fminf(fmaxf(rintf(v.z / s), -127.f), 127.f) * s;
    const float q3 = fminf(fmaxf(rintf(v.w / s), -127.f), 127.f) * s;
    ushort4 r;
    r.x = f32_to_bf16_rne(q0);
    r.y = f32_to_bf16_rne(q1);
    r.z = f32_to_bf16_rne(q2);
    r.w = f32_to_bf16_rne(q3);
    ((ushort4*)qx)[tid] = r;
}

// ---------------------------------------------------------------------------
// Fake-quantize weight (kept [Dout][Din] == B^T layout). 32x32 blocks.
// ---------------------------------------------------------------------------
__global__ void quant_w_kernel(const float* __restrict__ w, ushort* __restrict__ qw) {
    const int gtid = blockIdx.x * 256 + threadIdx.x;
    const int wid  = gtid >> 6;
    const int lane = gtid & 63;
    const int tn = wid >> 6;
    const int tk = wid & 63;
    const int row = tn * 32 + (lane >> 1);
    const int col = tk * 32 + ((lane & 1) << 4);
    const float* p = w + (size_t)row * K_TOT + col;
    const float4 v0 = ((const float4*)p)[0];
    const float4 v1 = ((const float4*)p)[1];
    const float4 v2 = ((const float4*)p)[2];
    const float4 v3 = ((const float4*)p)[3];
    float m = 0.f;
#define MAX4(V) m = fmaxf(m, fmaxf(fmaxf(fabsf(V.x), fabsf(V.y)), fmaxf(fabsf(V.z), fabsf(V.w))));
    MAX4(v0) MAX4(v1) MAX4(v2) MAX4(v3)
#undef MAX4
    #pragma unroll
    for (int off = 1; off < 64; off <<= 1) m = fmaxf(m, __shfl_xor(m, off));
    const float s = (m > 0.f) ? (m / 127.f) : 1.f;
    float vv[16] = {v0.x, v0.y, v0.z, v0.w, v1.x, v1.y, v1.z, v1.w,
                    v2.x, v2.y, v2.z, v2.w, v3.x, v3.y, v3.z, v3.w};
    union { ushort us[16]; uint4 q[2]; } o;
    #pragma unroll
    for (int i = 0; i < 16; ++i) {
        const float q = fminf(fmaxf(rintf(vv[i] / s), -127.f), 127.f) * s;
        o.us[i] = f32_to_bf16_rne(q);
    }
    uint4* dst = (uint4*)(qw + (size_t)row * K_TOT + col);
    dst[0] = o.q[0];
    dst[1] = o.q[1];
}

// ---------------------------------------------------------------------------
// 256x256 bf16 GEMM, register-rotated phase pipeline:
//   phase p issues phase p+1's ds_reads (alt reg set), waits lgkmcnt(4)
//   (drains only the OLDER reads, which completed under p-1's MFMA), then
//   runs 16 MFMA.  LDS drain overlaps MFMA.  2 barriers per K-tile:
//   end-p1 (B(t+2)-stage vs bg-read WAR), end-p3 (vmcnt(4) RAW on staged).
// ---------------------------------------------------------------------------
#define LDSA(tb, row, colus) \
    (*(const bf16x8*)&As[tb][row][(colus) ^ (((row) & 7) << 3)])
#define LDSB(tb, row, colus) \
    (*(const bf16x8*)&Bs[tb][row][(colus) ^ (((row) & 7) << 3)])

#define STAGE_A(tb, hh, li, tt)                                                          \
    async_copy16(Agbase + (size_t)((hh) * 128 + (li) * 64) * K_TOT + (size_t)(tt) * 64,  \
                 (char*)&As[0][0][0] + (tb) * 32768 + (hh) * 16384 + (li) * 8192 + (wv << 10));
#define STAGE_B(tb, hh, li, tt)                                                          \
    async_copy16(Bgbase + (size_t)((hh) * 128 + (li) * 64) * K_TOT + (size_t)(tt) * 64,  \
                 (char*)&Bs[0][0][0] + (tb) * 32768 + (hh) * 16384 + (li) * 8192 + (wv << 10));
#define STAGE_A2(tb, hh, tt)  { STAGE_A(tb, hh, 0, tt) STAGE_A(tb, hh, 1, tt) }
#define STAGE_B2(tb, hh, tt)  { STAGE_B(tb, hh, 0, tt) STAGE_B(tb, hh, 1, tt) }

#define WAITLGKM4 { asm volatile("s_waitcnt lgkmcnt(4)" ::: "memory"); __builtin_amdgcn_sched_barrier(0); }
#define WAITLGKM0 { asm volatile("s_waitcnt lgkmcnt(0)" ::: "memory"); __builtin_amdgcn_sched_barrier(0); }
#define WAITVM4   { asm volatile("s_waitcnt vmcnt(4)" ::: "memory"); }
#define WAITVM0   { asm volatile("s_waitcnt vmcnt(0)" ::: "memory"); }

// read the 4 A-fragments of row-pair q (rows q*32, q*32+16; k lo/hi halves)
#define RD_AF(DST, tb, q) {                                   \
    DST[0] = LDSA(tb, ab + (q) * 32,      h8);                \
    DST[1] = LDSA(tb, ab + (q) * 32,      32 + h8);           \
    DST[2] = LDSA(tb, ab + (q) * 32 + 16, h8);                \
    DST[3] = LDSA(tb, ab + (q) * 32 + 16, 32 + h8); }

#define MFMA_PH(i0, AF)                                                                   \
    __builtin_amdgcn_s_setprio(1);                                                        \
    _Pragma("unroll")                                                                     \
    for (int j = 0; j < 4; ++j) {                                                         \
        acc[i0][j]     = __builtin_amdgcn_mfma_f32_16x16x32_bf16(AF[0], bg[j][0], acc[i0][j], 0, 0, 0);     \
        acc[i0][j]     = __builtin_amdgcn_mfma_f32_16x16x32_bf16(AF[1], bg[j][1], acc[i0][j], 0, 0, 0);     \
        acc[(i0)+1][j] = __builtin_amdgcn_mfma_f32_16x16x32_bf16(AF[2], bg[j][0], acc[(i0)+1][j], 0, 0, 0); \
        acc[(i0)+1][j] = __builtin_amdgcn_mfma_f32_16x16x32_bf16(AF[3], bg[j][1], acc[(i0)+1][j], 0, 0, 0); \
    }                                                                                     \
    __builtin_amdgcn_s_setprio(0);

// One K-tile.  STA: stage A(t+1); STB: stage B(t+2); VMC: 4 / 0 / -1 (skip).
#define TILE_BODY(tb, t, STA, STB, VMC)                                                   \
  {                                                                                       \
    /* -- p0: issue af(p0)+bg (12) + af(p1) (4); stage A(t+1)h0; drain 12 -- */           \
    RD_AF(afX, tb, 0)                                                                     \
    _Pragma("unroll")                                                                     \
    for (int j = 0; j < 4; ++j) {                                                         \
        const int bb = wcn * 64 + j * 16 + r;                                             \
        bg[j][0] = LDSB(tb, bb, h8);  bg[j][1] = LDSB(tb, bb, 32 + h8);                   \
    }                                                                                     \
    RD_AF(afY, tb, 1)                                                                     \
    if (STA) STAGE_A2(tb ^ 1, 0, (t) + 1)                                                 \
    WAITLGKM4                                                                             \
    MFMA_PH(0, afX)                                                                       \
    /* -- p1: issue af(p2); stage A(t+1)h1; MFMA on afY -- */                             \
    RD_AF(afX, tb, 2)                                                                     \
    if (STA) STAGE_A2(tb ^ 1, 1, (t) + 1)                                                 \
    WAITLGKM4                                                                             \
    MFMA_PH(2, afY)                                                                       \
    __builtin_amdgcn_s_barrier();  /* all bg reads served -> B-stage safe */              \
    /* -- p2: issue af(p3); stage B(t+2)h0; MFMA on afX -- */                             \
    RD_AF(afY, tb, 3)                                                                     \
    if (STB) STAGE_B2(tb, 0, (t) + 2)                                                     \
    WAITLGKM4                                                                             \
    MFMA_PH(4, afX)                                                                       \
    /* -- p3: stage B(t+2)h1; MFMA on afY; counted vmcnt; barrier -- */                   \
    if (STB) STAGE_B2(tb, 1, (t) + 2)                                                     \
    WAITLGKM0                                                                             \
    MFMA_PH(6, afY)                                                                       \
    if ((VMC) == 4)      WAITVM4                                                          \
    else if ((VMC) == 0) WAITVM0                                                          \
    __builtin_amdgcn_s_barrier();  /* staged A(t+1)/B(t+1) visible */                     \
  }

__global__ __launch_bounds__(512, 2) void gemm_pipe2_kernel(
    const ushort* __restrict__ A,    // [M][K] bf16 bits
    const ushort* __restrict__ Bt,   // [N][K] bf16 bits
    const float* __restrict__ bias,  // [N]
    float* __restrict__ C) {         // [M][N]

    __shared__ ushort As[2][256][64];   // 64 KB
    __shared__ ushort Bs[2][256][64];   // 64 KB

    const int tid  = threadIdx.x;
    const int lane = tid & 63;
    const int wv   = tid >> 6;          // wave 0..7
    const int wmr  = wv >> 2;           // 0..1  (M)
    const int wcn  = wv & 3;            // 0..3  (N)
    const int r    = lane & 15;
    const int h8   = (lane >> 4) << 3;  // 0,8,16,24 (ushort col of k-frag)

    // bijective XCD swizzle (nwg = 512)
    const int nbn  = N_TOT / 256;                 // 8
    const int nwg  = (M_TOT / 256) * nbn;         // 512
    const int cpx  = nwg >> 3;
    const int swz  = (blockIdx.x & 7) * cpx + (blockIdx.x >> 3);
    const int brow = (swz / nbn) * 256;
    const int bcol = (swz % nbn) * 256;

    // staging: thread -> row tid>>3 of each 64-row group, 16B at pre-swizzled col
    const int srow = tid >> 3;
    const int scol = (((tid & 7) ^ (srow & 7)) << 3);
    const ushort* Agbase = A  + (size_t)(brow + srow) * K_TOT + scol;
    const ushort* Bgbase = Bt + (size_t)(bcol + srow) * K_TOT + scol;

    const int ab = wmr * 128 + r;       // wave's A row base

    f32x4 acc[8][4];
    const f32x4 zero = {0.f, 0.f, 0.f, 0.f};
    #pragma unroll
    for (int i = 0; i < 8; ++i)
        #pragma unroll
        for (int j = 0; j < 4; ++j) acc[i][j] = zero;

    // ---- prologue: A(0)+B(0)+B(1); full drain; barrier ----
    STAGE_A2(0, 0, 0) STAGE_A2(0, 1, 0)
    STAGE_B2(0, 0, 0) STAGE_B2(0, 1, 0)
    STAGE_B2(1, 0, 1) STAGE_B2(1, 1, 1)
    WAITVM0
    __builtin_amdgcn_s_barrier();

    bf16x8 afX[4], afY[4];
    bf16x8 bg[4][2];

    for (int t = 0; t < NT - 2; t += 2) {
        TILE_BODY(0, t,     1, 1, 4)
        TILE_BODY(1, t + 1, 1, 1, 4)
    }
    TILE_BODY(0, NT - 2, 1, 0, 0)    // stage A(31) only; drain all
    TILE_BODY(1, NT - 1, 0, 0, -1)   // no staging, no vmcnt

    // ---- epilogue: bias + store (C/D layout: col=lane&15, row=(lane>>4)*4+reg)
    const int hq = (lane >> 4) * 4;
    float bv[4];
    #pragma unroll
    for (int j = 0; j < 4; ++j) bv[j] = bias[bcol + wcn * 64 + j * 16 + r];
    #pragma unroll
    for (int i = 0; i < 8; ++i) {
        const int row0 = brow + wmr * 128 + i * 16 + hq;
        #pragma unroll
        for (int j = 0; j < 4; ++j) {
            const int col = bcol + wcn * 64 + j * 16 + r;
            #pragma unroll
            for (int jj = 0; jj < 4; ++jj)
                C[(size_t)(row0 + jj) * N_TOT + col] = acc[i][j][jj] + bv[j];
        }
    }
}

extern "C" void kernel_launch(void* const* d_in, const int* in_sizes, int n_in,
                              void* d_out, int out_size, void* d_ws, size_t ws_size,
                              hipStream_t stream) {
    const float* x    = (const float*)d_in[0];   // [4,4096,2048]
    const float* wgt  = (const float*)d_in[1];   // [2048,2048]
    const float* bias = (const float*)d_in[2];   // [2048]
    float* out = (float*)d_out;                  // [4,4096,2048]

    ushort* qx = (ushort*)d_ws;                          // 64 MB
    ushort* qw = qx + (size_t)M_TOT * K_TOT;             // 8 MB

    quant_x_kernel<<<(M_TOT * K_TOT / 4) / 256, 256, 0, stream>>>(x, qx);
    quant_w_kernel<<<(64 * 64 * 64) / 256, 256, 0, stream>>>(wgt, qw);
    gemm_pipe2_kernel<<<(M_TOT / 256) * (N_TOT / 256), 512, 0, stream>>>(qx, qw, bias, out);
}